// Round 13
// baseline (161.868 us; speedup 1.0000x reference)
//
#include <hip/hip_runtime.h>

// SEIR SDE: B=32768 x 1000 steps -> out[step][4][B] f32 = 524 MB (write-bound).
// Ladder: 242 -> 115.6 -> 97.2 (R7 producer/consumer) -> 94.2 (R12 double
// register sets for stores-in-flight). Falsified as limiters: barrier drain
// (R8), compute-wave LDS (R11), noise prefetch (R3), in-flight depth alone
// (R12 small win). Remaining gap: 226 vs 183 cyc/step floor, i.e. 865
// cyc/chunk. Candidates: (a) single store wave per block absorbs the whole
// 20KB burst + backpressure alone (2 storing waves/CU vs fillBuffer's ~4);
// (b) 256B-segment pattern ceiling (~5.6 TB/s, unfixable at this layout).
// R13 tests (a): block=256 = 1 compute wave + THREE store waves (chunk split
// 7/7/6 steps). 6 store waves/CU: 3x issue width, 3x aggregate vmcnt depth.
// Everything else verbatim R12 (validated absmax 0.0).

constexpr int   B_TRAJ  = 32768;
constexpr int   NSTEPS  = 1000;
constexpr int   K       = 20;            // steps per chunk
constexpr int   NC      = NSTEPS / K;    // 50 chunks (even)
constexpr int   KW      = 7;             // max steps per store wave (7/7/6)
constexpr float DT      = 0.01f;
constexpr float EPS     = 1e-6f;
constexpr float INV_N   = 1.0f / 10000.0f;

// Barrier without vmcnt drain: LDS ordering only; global stores stay in
// flight across chunk boundaries.
__device__ __forceinline__ void barrier_lds_only() {
    asm volatile("s_waitcnt lgkmcnt(0)" ::: "memory");
    __builtin_amdgcn_s_barrier();
    asm volatile("" ::: "memory");
}

__global__ __launch_bounds__(256) void seir_sde_kernel(
    const float* __restrict__ beta,
    const float* __restrict__ sigma,
    const float* __restrict__ gamma,
    const float* __restrict__ S0,
    const float* __restrict__ E0,
    const float* __restrict__ I0,
    const float* __restrict__ R0,
    const float4* __restrict__ dW,   // [NSTEPS] raw (w0,w1,w2,w3)
    float* __restrict__ out)         // [NSTEPS][4][B_TRAJ]
{
    __shared__ float4 wbuf[NSTEPS];          // pre-scaled noise, 16 KB
    __shared__ float  ring[2][K][4][64];     // SoA chunk ring, 40 KB

    // Folded constants (3 scalar loads, once, all threads).
    const float btnD = beta[0] * INV_N * DT; // (beta/N)*DT
    const float sgD  = sigma[0] * DT;        // sigma*DT
    const float gmD  = gamma[0] * DT;        // gamma*DT
    const float sbi  = __builtin_amdgcn_sqrtf(btnD);
    const float sbe  = __builtin_amdgcn_sqrtf(sgD);
    const float sbr  = __builtin_amdgcn_sqrtf(gmD);

    // Stage noise pre-multiplied: per-step diffusion becomes sqrt(P)*w.
    for (int i = threadIdx.x; i < NSTEPS; i += 256) {
        const float4 w = dW[i];
        wbuf[i] = make_float4(w.x * sbi, w.y * sbe, w.z * sbr, 0.0f);
    }

    const int lane = threadIdx.x & 63;
    const int wid  = threadIdx.x >> 6;       // 0 = compute; 1..3 = store waves

    float S=0.f, E=0.f, I=0.f, R=0.f;
    if (wid == 0) {
        const int b = blockIdx.x * 64 + lane;
        S = S0[b]; E = E0[b]; I = I0[b]; R = R0[b];
    }

    // Store-wave k-range: wave 1 -> [0,7), wave 2 -> [7,14), wave 3 -> [14,20).
    const int k0 = (wid - 1) * KW;                    // valid for wid>=1
    const int nk = (wid == 3) ? (K - 2 * KW) : KW;    // 7,7,6

    // Store addressing: lane l -> component (l>>4), trajectories 4*(l&15)..+3.
    float* const obase = out + blockIdx.x * 64
                             + (lane >> 4) * B_TRAJ + (lane & 15) * 4;

    #define SEIR_STEP(w, dst)                                                  \
    {                                                                          \
        const float Sc = fmaxf(S, EPS);                                        \
        const float Ec = fmaxf(E, EPS);                                        \
        const float Ic = fmaxf(I, EPS);                                        \
        const float Rc = fmaxf(R, EPS);                                        \
        const float P  = Sc * Ic;                                              \
        const float iD = btnD * P;                                             \
        const float eD = sgD * Ec;                                             \
        const float rD = gmD * Ic;                                             \
        const float ai = __builtin_amdgcn_sqrtf(P)  * (w).x;                   \
        const float ae = __builtin_amdgcn_sqrtf(Ec) * (w).y;                   \
        const float ar = __builtin_amdgcn_sqrtf(Ic) * (w).z;                   \
        const float Sn = Sc - iD - ai;                                         \
        const float En = Ec + iD - eD + ai - ae;                               \
        const float In = Ic + eD - rD + ae - ar;                               \
        const float Rn = Rc + rD + ar;                                         \
        (dst)[0][lane] = Sn;                                                   \
        (dst)[1][lane] = En;                                                   \
        (dst)[2][lane] = In;                                                   \
        (dst)[3][lane] = Rn;                                                   \
        S = Sn; E = En; I = In; R = Rn;                                        \
    }

    #define FILL(c)                                                            \
    {                                                                          \
        const int s0 = (c) * K;                                                \
        float (*rw)[4][64] = ring[(c) & 1];                                    \
        _Pragma("unroll")                                                      \
        for (int k = 0; k < K; ++k) {                                          \
            const float4 w = wbuf[s0 + k];                                     \
            SEIR_STEP(w, rw[k]);                                               \
        }                                                                      \
    }

    // Store wave drains its k-slice of chunk c via register set v (KW-deep).
    // Alternating sets across chunks => WAR wait is a counted vmcnt, keeping
    // a full slice of stores in flight permanently.
    #define STORE_CHUNK(c, v)                                                  \
    {                                                                          \
        const float4* rd = (const float4*)&ring[(c) & 1][k0][0][0];            \
        float* o = obase + (size_t)((c) * K + k0) * (4 * B_TRAJ);              \
        _Pragma("unroll")                                                      \
        for (int k = 0; k < KW; ++k)                                           \
            if (k < nk) v[k] = rd[k * 64 + lane];                              \
        _Pragma("unroll")                                                      \
        for (int k = 0; k < KW; ++k)                                           \
            if (k < nk) {                                                      \
                *(float4*)o = v[k];                                            \
                o += 4 * B_TRAJ;                                               \
            }                                                                  \
    }

    float4 va[KW], vb[KW];                   // two in-flight store sets

    __syncthreads();                         // noise staged (once; drain ok)

    // ---- prologue: compute wave fills chunk 0 ----
    if (wid == 0) FILL(0);
    barrier_lds_only();

    // ---- pipeline, 2 chunks per iteration (NC even) ----
    for (int cc = 0; cc < NC; cc += 2) {
        if (wid == 0) { FILL(cc + 1); }
        else          { STORE_CHUNK(cc, va); }
        barrier_lds_only();
        if (wid == 0) { if (cc + 2 < NC) FILL(cc + 2); }
        else          { STORE_CHUNK(cc + 1, vb); }
        barrier_lds_only();
    }
    #undef SEIR_STEP
    #undef FILL
    #undef STORE_CHUNK
}

extern "C" void kernel_launch(void* const* d_in, const int* in_sizes, int n_in,
                              void* d_out, int out_size, void* d_ws, size_t ws_size,
                              hipStream_t stream) {
    const float*  beta  = (const float*)d_in[0];
    const float*  sigma = (const float*)d_in[1];
    const float*  gamma = (const float*)d_in[2];
    const float*  S0    = (const float*)d_in[3];
    const float*  E0    = (const float*)d_in[4];
    const float*  I0    = (const float*)d_in[5];
    const float*  R0    = (const float*)d_in[6];
    const float4* dW    = (const float4*)d_in[7];
    float* out = (float*)d_out;

    seir_sde_kernel<<<B_TRAJ / 64, 256, 0, stream>>>(
        beta, sigma, gamma, S0, E0, I0, R0, dW, out);
}

// Round 14
// 94.455 us; speedup vs baseline: 1.7137x; 1.7137x over previous
//
#include <hip/hip_runtime.h>

// SEIR SDE: B=32768 x 1000 steps -> out[step][4][B] f32 = 524 MB (write-bound).
// Ladder: 242 -> 115.6 -> 97.2 (R7 producer/consumer) -> 94.2 (R12 in-flight
// store reg-sets). Falsified: barrier drain (R8), compute-LDS (R11), prefetch
// (R3), store issue width (R13 regressed, reverted). Remaining theory: block
// b's entire output stream differs only in addr bits [0,256B) -> concentrates
// on ~1 HBM channel; its channel-mates {b+128,b+256,b+384} are same-XCD under
// round-robin dispatch -> correlated bursts into one channel queue. R14 =
// R12 + canonical bijective XCD swizzle (nwg=512 % 8 == 0): each XCD owns a
// contiguous block range, decorrelating channel from XCD and from timing.

constexpr int   B_TRAJ  = 32768;
constexpr int   NSTEPS  = 1000;
constexpr int   K       = 20;            // steps per chunk
constexpr int   NC      = NSTEPS / K;    // 50 chunks (even)
constexpr float DT      = 0.01f;
constexpr float EPS     = 1e-6f;
constexpr float INV_N   = 1.0f / 10000.0f;

// Barrier without vmcnt drain: LDS ordering only; global stores stay in
// flight across chunk boundaries.
__device__ __forceinline__ void barrier_lds_only() {
    asm volatile("s_waitcnt lgkmcnt(0)" ::: "memory");
    __builtin_amdgcn_s_barrier();
    asm volatile("" ::: "memory");
}

__global__ __launch_bounds__(128) void seir_sde_kernel(
    const float* __restrict__ beta,
    const float* __restrict__ sigma,
    const float* __restrict__ gamma,
    const float* __restrict__ S0,
    const float* __restrict__ E0,
    const float* __restrict__ I0,
    const float* __restrict__ R0,
    const float4* __restrict__ dW,   // [NSTEPS] raw (w0,w1,w2,w3)
    float* __restrict__ out)         // [NSTEPS][4][B_TRAJ]
{
    __shared__ float4 wbuf[NSTEPS];          // pre-scaled noise, 16 KB
    __shared__ float  ring[2][K][4][64];     // SoA chunk ring, 40 KB

    // Bijective XCD swizzle (nwg = 512, divisible by 8): XCD x = b&7 gets the
    // contiguous block range [x*64, (x+1)*64) -> its 64 co-resident blocks
    // write 64 DIFFERENT 256B address slots instead of stacking on one.
    const int xb = (blockIdx.x & 7) * 64 + (blockIdx.x >> 3);

    // Folded constants (3 scalar loads, once, all threads).
    const float btnD = beta[0] * INV_N * DT; // (beta/N)*DT
    const float sgD  = sigma[0] * DT;        // sigma*DT
    const float gmD  = gamma[0] * DT;        // gamma*DT
    const float sbi  = __builtin_amdgcn_sqrtf(btnD);
    const float sbe  = __builtin_amdgcn_sqrtf(sgD);
    const float sbr  = __builtin_amdgcn_sqrtf(gmD);

    // Stage noise pre-multiplied: per-step diffusion becomes sqrt(P)*w.
    for (int i = threadIdx.x; i < NSTEPS; i += 128) {
        const float4 w = dW[i];
        wbuf[i] = make_float4(w.x * sbi, w.y * sbe, w.z * sbr, 0.0f);
    }

    const int lane = threadIdx.x & 63;
    const int wid  = threadIdx.x >> 6;       // 0 = compute wave, 1 = store wave

    float S=0.f, E=0.f, I=0.f, R=0.f;
    if (wid == 0) {
        const int b = xb * 64 + lane;
        S = S0[b]; E = E0[b]; I = I0[b]; R = R0[b];
    }

    // Store-wave addressing: lane l -> component (l>>4), trajectories
    // 4*(l&15)..+3 of this block. One dwordx4 = 4 x 256B segments.
    float* const obase = out + xb * 64
                             + (lane >> 4) * B_TRAJ + (lane & 15) * 4;

    // One SEIR step. sqrt(rate*DT)*w_raw == sqrt(P)*(sqrt(const)*w_raw) with
    // the uniform factor folded into wbuf at staging (validated regrouping).
    #define SEIR_STEP(w, dst)                                                  \
    {                                                                          \
        const float Sc = fmaxf(S, EPS);                                        \
        const float Ec = fmaxf(E, EPS);                                        \
        const float Ic = fmaxf(I, EPS);                                        \
        const float Rc = fmaxf(R, EPS);                                        \
        const float P  = Sc * Ic;                                              \
        const float iD = btnD * P;                                             \
        const float eD = sgD * Ec;                                             \
        const float rD = gmD * Ic;                                             \
        const float ai = __builtin_amdgcn_sqrtf(P)  * (w).x;                   \
        const float ae = __builtin_amdgcn_sqrtf(Ec) * (w).y;                   \
        const float ar = __builtin_amdgcn_sqrtf(Ic) * (w).z;                   \
        const float Sn = Sc - iD - ai;                                         \
        const float En = Ec + iD - eD + ai - ae;                               \
        const float In = Ic + eD - rD + ae - ar;                               \
        const float Rn = Rc + rD + ar;                                         \
        (dst)[0][lane] = Sn;                                                   \
        (dst)[1][lane] = En;                                                   \
        (dst)[2][lane] = In;                                                   \
        (dst)[3][lane] = Rn;                                                   \
        S = Sn; E = En; I = In; R = Rn;                                        \
    }

    // Compute wave: fill chunk c into ring[c&1].
    #define FILL(c)                                                            \
    {                                                                          \
        const int s0 = (c) * K;                                                \
        float (*rw)[4][64] = ring[(c) & 1];                                    \
        _Pragma("unroll")                                                      \
        for (int k = 0; k < K; ++k) {                                          \
            const float4 w = wbuf[s0 + k];                                     \
            SEIR_STEP(w, rw[k]);                                               \
        }                                                                      \
    }

    // Store wave: drain chunk c through register set v (20 b128 reads, then
    // 20 dwordx4 stores). Alternating v sets across chunks => compiler's WAR
    // wait is vmcnt(~K), keeping a full chunk of stores in flight always.
    #define STORE_CHUNK(c, v)                                                  \
    {                                                                          \
        const float4* rd = (const float4*)&ring[(c) & 1][0][0][0];             \
        float* o = obase + (size_t)((c) * K) * (4 * B_TRAJ);                   \
        _Pragma("unroll")                                                      \
        for (int k = 0; k < K; ++k) v[k] = rd[k * 64 + lane];                  \
        _Pragma("unroll")                                                      \
        for (int k = 0; k < K; ++k) {                                          \
            *(float4*)o = v[k];                                                \
            o += 4 * B_TRAJ;                                                   \
        }                                                                      \
    }

    float4 va[K], vb[K];                     // two in-flight store sets

    __syncthreads();                         // noise staged (once; drain ok)

    // ---- prologue: compute wave fills chunk 0 ----
    if (wid == 0) FILL(0);
    barrier_lds_only();

    // ---- pipeline, 2 chunks per iteration (NC even) ----
    for (int cc = 0; cc < NC; cc += 2) {
        if (wid == 0) { FILL(cc + 1); }
        else          { STORE_CHUNK(cc, va); }
        barrier_lds_only();
        if (wid == 0) { if (cc + 2 < NC) FILL(cc + 2); }
        else          { STORE_CHUNK(cc + 1, vb); }
        barrier_lds_only();
    }
    #undef SEIR_STEP
    #undef FILL
    #undef STORE_CHUNK
}

extern "C" void kernel_launch(void* const* d_in, const int* in_sizes, int n_in,
                              void* d_out, int out_size, void* d_ws, size_t ws_size,
                              hipStream_t stream) {
    const float*  beta  = (const float*)d_in[0];
    const float*  sigma = (const float*)d_in[1];
    const float*  gamma = (const float*)d_in[2];
    const float*  S0    = (const float*)d_in[3];
    const float*  E0    = (const float*)d_in[4];
    const float*  I0    = (const float*)d_in[5];
    const float*  R0    = (const float*)d_in[6];
    const float4* dW    = (const float4*)d_in[7];
    float* out = (float*)d_out;

    seir_sde_kernel<<<B_TRAJ / 64, 128, 0, stream>>>(
        beta, sigma, gamma, S0, E0, I0, R0, dW, out);
}